// Round 4
// baseline (1395.638 us; speedup 1.0000x reference)
//
#include <hip/hip_runtime.h>
#include <math.h>

#define D 64

// ---------------- degree / dinv ----------------
__global__ void k_deg_init(float* deg, int n) {
    int i = blockIdx.x * blockDim.x + threadIdx.x;
    if (i < n) deg[i] = 1.0f;                     // self-loop contribution
}

__global__ void k_deg_edges(const int* __restrict__ dst, float* deg, int e) {
    int i = blockIdx.x * blockDim.x + threadIdx.x;
    if (i < e) atomicAdd(&deg[dst[i]], 1.0f);     // exact: integer counts < 2^24
}

__global__ void k_dinv(float* deg, int n) {
    int i = blockIdx.x * blockDim.x + threadIdx.x;
    if (i < n) deg[i] = rsqrtf(deg[i]);           // in place: deg -> dinv
}

// ---------------- fused: hws = (h @ W) * dinv[row];  agg = hws * dinv[row] ----------------
// K = 9 or 64, out dim = 64. One wave-row per 64 lanes; W staged in LDS.
template <int K>
__global__ void k_matmul(const float* __restrict__ h, const float* __restrict__ W,
                         const float* __restrict__ dinv,
                         float* __restrict__ hws, float* __restrict__ agg, int n) {
    __shared__ float sW[K * D];
    for (int i = threadIdx.x; i < K * D; i += blockDim.x) sW[i] = W[i];
    __syncthreads();
    int col = threadIdx.x & 63;
    int rl  = threadIdx.x >> 6;
    int row = blockIdx.x * (blockDim.x >> 6) + rl;
    if (row >= n) return;
    const float* hr = h + (long)row * K;
    float acc = 0.0f;
#pragma unroll
    for (int k = 0; k < K; ++k) acc = fmaf(hr[k], sW[k * D + col], acc);
    float di = dinv[row];
    float v  = acc * di;                 // pre-scaled by source-side norm
    hws[(long)row * D + col] = v;
    agg[(long)row * D + col] = v * di;   // self-loop: h*W*dinv^2
}

// ---------------- edge scatter: one wave (64 lanes = 64 cols) per edge ----------------
__global__ void k_edge(const int* __restrict__ src, const int* __restrict__ dst,
                       const float* __restrict__ dinv, const float* __restrict__ hws,
                       float* agg, int e) {
    int eid  = blockIdx.x * (blockDim.x >> 6) + (threadIdx.x >> 6);
    int lane = threadIdx.x & 63;
    if (eid >= e) return;
    int s = src[eid], d = dst[eid];
    float nd = dinv[d];
    atomicAdd(&agg[(long)d * D + lane], hws[(long)s * D + lane] * nd);
}

// ---------------- h = tanh(agg + b) ----------------
__global__ void k_biastanh(float* h, const float* __restrict__ b, long total) {
    long i = (long)blockIdx.x * blockDim.x + threadIdx.x;
    if (i < total) h[i] = tanhf(h[i] + b[i & 63]);
}

// ---------------- per-graph pool + output head ----------------
__global__ void k_pool(const float* __restrict__ h, const int* __restrict__ batch,
                       const float* __restrict__ Wout, const float* __restrict__ bout,
                       float* __restrict__ out, float* __restrict__ hidden, int n) {
    int g = blockIdx.x;
    // lower_bound(batch, g) and lower_bound(batch, g+1): batch is sorted
    int lo = 0, hi = n;
    while (lo < hi) { int mid = (lo + hi) >> 1; if (batch[mid] < g) lo = mid + 1; else hi = mid; }
    int start = lo;
    hi = n;
    while (lo < hi) { int mid = (lo + hi) >> 1; if (batch[mid] < g + 1) lo = mid + 1; else hi = mid; }
    int end = lo;

    int j = threadIdx.x;  // 0..63, one lane per feature column
    float mx = -INFINITY, sm = 0.0f;
    for (int nd = start; nd < end; ++nd) {
        float v = h[(long)nd * D + j];
        mx = fmaxf(mx, v);
        sm += v;
    }
    float gmax  = (end > start) ? mx : 0.0f;   // isfinite guard for empty graphs
    float gmean = sm / fmaxf((float)(end - start), 1.0f);

    hidden[(long)g * 2 * D + j]     = gmax;
    hidden[(long)g * 2 * D + D + j] = gmean;

    float p = gmax * Wout[j] + gmean * Wout[D + j];
#pragma unroll
    for (int off = 32; off > 0; off >>= 1) p += __shfl_down(p, off, 64);
    if (j == 0) out[g] = p + bout[0];
}

extern "C" void kernel_launch(void* const* d_in, const int* in_sizes, int n_in,
                              void* d_out, int out_size, void* d_ws, size_t ws_size,
                              hipStream_t stream) {
    const float* x     = (const float*)d_in[0];
    const int*   ei    = (const int*)d_in[1];
    const int*   batch = (const int*)d_in[2];
    const float* W0 = (const float*)d_in[3];  const float* b0 = (const float*)d_in[4];
    const float* W1 = (const float*)d_in[5];  const float* b1 = (const float*)d_in[6];
    const float* W2 = (const float*)d_in[7];  const float* b2 = (const float*)d_in[8];
    const float* W3 = (const float*)d_in[9];  const float* b3 = (const float*)d_in[10];
    const float* Wout = (const float*)d_in[11];
    const float* bout = (const float*)d_in[12];
    float* out = (float*)d_out;

    const int N = in_sizes[0] / 9;
    const int E = in_sizes[1] / 2;
    const int G = out_size / (2 * D + 1);   // out (G) + hidden (G*128)
    const int* src = ei;
    const int* dst = ei + E;

    float* hidden = out + G;

    // workspace layout (all fully initialized by kernels below; ws is poisoned)
    char* ws = (char*)d_ws;
    size_t off = 0;
    auto alloc = [&](size_t bytes) { void* p = ws + off; off += (bytes + 255) & ~(size_t)255; return p; };
    float* dinv = (float*)alloc((size_t)N * sizeof(float));
    float* buf0 = (float*)alloc((size_t)N * D * sizeof(float));   // agg / activations
    float* buf1 = (float*)alloc((size_t)N * D * sizeof(float));   // hws = (h @ W) * dinv

    const int T = 256;
    const long ND = (long)N * D;
    const int gridND = (int)((ND + T - 1) / T);

    // degree -> dinv (in place in `dinv` buffer)
    k_deg_init<<<(N + T - 1) / T, T, 0, stream>>>(dinv, N);
    k_deg_edges<<<(E + T - 1) / T, T, 0, stream>>>(dst, dinv, E);
    k_dinv<<<(N + T - 1) / T, T, 0, stream>>>(dinv, N);

    auto layer = [&](const float* hin, int K, const float* W, const float* b) {
        // buf1 = (hin @ W)*dinv ; buf0 = self-loop init (full overwrite)
        if (K == 9)
            k_matmul<9><<<(N + 3) / 4, T, 0, stream>>>(hin, W, dinv, buf1, buf0, N);
        else
            k_matmul<64><<<(N + 3) / 4, T, 0, stream>>>(hin, W, dinv, buf1, buf0, N);
        // agg += scatter over edges
        k_edge<<<(E + 3) / 4, T, 0, stream>>>(src, dst, dinv, buf1, buf0, E);
        // h = tanh(agg + b)  in place in buf0
        k_biastanh<<<gridND, T, 0, stream>>>(buf0, b, ND);
    };

    layer(x,    9,  W0, b0);
    layer(buf0, 64, W1, b1);
    layer(buf0, 64, W2, b2);
    layer(buf0, 64, W3, b3);

    k_pool<<<G, 64, 0, stream>>>(buf0, batch, Wout, bout, out, hidden, N);
}

// Round 5
// 689.165 us; speedup vs baseline: 2.0251x; 2.0251x over previous
//
#include <hip/hip_runtime.h>
#include <math.h>

#define D 64

// ---------------- CSR build ----------------
__global__ void k_zero(int* p, int n) {
    int i = blockIdx.x * blockDim.x + threadIdx.x;
    if (i < n) p[i] = 0;
}

__global__ void k_hist(const int* __restrict__ dst, int* __restrict__ counts, int e) {
    int i = blockIdx.x * blockDim.x + threadIdx.x;
    if (i < e) atomicAdd(&counts[dst[i]], 1);
}

// dinv = rsqrt(deg+1)  (self-loop included in degree)
__global__ void k_dinv(const int* __restrict__ counts, float* __restrict__ dinv, int n) {
    int i = blockIdx.x * blockDim.x + threadIdx.x;
    if (i < n) dinv[i] = rsqrtf((float)counts[i] + 1.0f);
}

// single-block exclusive scan; counts[i] is overwritten with the same prefix (scatter cursor)
__global__ void k_scan(int* __restrict__ counts, int* __restrict__ rowptr, int n) {
    __shared__ int part[1024];
    int t = threadIdx.x;
    int chunk = (n + 1023) >> 10;
    int lo = t * chunk, hi = min(lo + chunk, n);
    int s = 0;
    for (int i = lo; i < hi; ++i) s += counts[i];
    part[t] = s;
    __syncthreads();
    for (int off = 1; off < 1024; off <<= 1) {
        int v = (t >= off) ? part[t - off] : 0;
        __syncthreads();
        part[t] += v;
        __syncthreads();
    }
    int base = (t == 0) ? 0 : part[t - 1];
    for (int i = lo; i < hi; ++i) { int c = counts[i]; rowptr[i] = base; counts[i] = base; base += c; }
    if (t == 1023) rowptr[n] = part[1023];
}

__global__ void k_scatter(const int* __restrict__ src, const int* __restrict__ dst,
                          int* __restrict__ cur, int* __restrict__ ssrc, int e) {
    int i = blockIdx.x * blockDim.x + threadIdx.x;
    if (i < e) { int p = atomicAdd(&cur[dst[i]], 1); ssrc[p] = src[i]; }
}

// ---------------- hws = (h @ W) * dinv[row] ----------------
template <int K>
__global__ void k_matmul(const float* __restrict__ h, const float* __restrict__ W,
                         const float* __restrict__ dinv, float* __restrict__ hws, int n) {
    __shared__ float sW[K * D];
    for (int i = threadIdx.x; i < K * D; i += blockDim.x) sW[i] = W[i];
    __syncthreads();
    int col = threadIdx.x & 63;
    int row = blockIdx.x * (blockDim.x >> 6) + (threadIdx.x >> 6);
    if (row >= n) return;
    const float* hr = h + (long)row * K;
    float acc = 0.0f;
#pragma unroll
    for (int k = 0; k < K; ++k) acc = fmaf(hr[k], sW[k * D + col], acc);
    hws[row * D + col] = acc * dinv[row];
}

// ---------------- pull-aggregate + bias + tanh (fused) ----------------
// agg[d] = dinv[d] * (sum_{s in N(d)} hws[s] + hws[d]);  h = tanh(agg + b)
__global__ void k_aggregate(const int* __restrict__ rowptr, const int* __restrict__ ssrc,
                            const float* __restrict__ dinv, const float* __restrict__ hws,
                            const float* __restrict__ b, float* __restrict__ hout, int n) {
    int node = blockIdx.x * (blockDim.x >> 6) + (threadIdx.x >> 6);
    int lane = threadIdx.x & 63;
    if (node >= n) return;
    int beg = rowptr[node], end = rowptr[node + 1];
    float acc = hws[node * D + lane];            // self-loop
    int e = beg;
    for (; e + 4 <= end; e += 4) {               // unroll-4 for load ILP
        int s0 = ssrc[e], s1 = ssrc[e + 1], s2 = ssrc[e + 2], s3 = ssrc[e + 3];
        float a0 = hws[s0 * D + lane], a1 = hws[s1 * D + lane];
        float a2 = hws[s2 * D + lane], a3 = hws[s3 * D + lane];
        acc += a0; acc += a1; acc += a2; acc += a3;
    }
    for (; e < end; ++e) acc += hws[ssrc[e] * D + lane];
    hout[node * D + lane] = tanhf(acc * dinv[node] + b[lane]);
}

// ---------------- per-graph pool + output head ----------------
__global__ void k_pool(const float* __restrict__ h, const int* __restrict__ batch,
                       const float* __restrict__ Wout, const float* __restrict__ bout,
                       float* __restrict__ out, float* __restrict__ hidden, int n) {
    int g = blockIdx.x;
    int lo = 0, hi = n;
    while (lo < hi) { int mid = (lo + hi) >> 1; if (batch[mid] < g) lo = mid + 1; else hi = mid; }
    int start = lo;
    hi = n;
    while (lo < hi) { int mid = (lo + hi) >> 1; if (batch[mid] < g + 1) lo = mid + 1; else hi = mid; }
    int end = lo;

    int j = threadIdx.x;
    float mx = -INFINITY, sm = 0.0f;
    for (int nd = start; nd < end; ++nd) {
        float v = h[nd * D + j];
        mx = fmaxf(mx, v);
        sm += v;
    }
    float gmax  = (end > start) ? mx : 0.0f;
    float gmean = sm / fmaxf((float)(end - start), 1.0f);

    hidden[g * 2 * D + j]     = gmax;
    hidden[g * 2 * D + D + j] = gmean;

    float p = gmax * Wout[j] + gmean * Wout[D + j];
#pragma unroll
    for (int off = 32; off > 0; off >>= 1) p += __shfl_down(p, off, 64);
    if (j == 0) out[g] = p + bout[0];
}

extern "C" void kernel_launch(void* const* d_in, const int* in_sizes, int n_in,
                              void* d_out, int out_size, void* d_ws, size_t ws_size,
                              hipStream_t stream) {
    const float* x     = (const float*)d_in[0];
    const int*   ei    = (const int*)d_in[1];
    const int*   batch = (const int*)d_in[2];
    const float* W0 = (const float*)d_in[3];  const float* b0 = (const float*)d_in[4];
    const float* W1 = (const float*)d_in[5];  const float* b1 = (const float*)d_in[6];
    const float* W2 = (const float*)d_in[7];  const float* b2 = (const float*)d_in[8];
    const float* W3 = (const float*)d_in[9];  const float* b3 = (const float*)d_in[10];
    const float* Wout = (const float*)d_in[11];
    const float* bout = (const float*)d_in[12];
    float* out = (float*)d_out;

    const int N = in_sizes[0] / 9;
    const int E = in_sizes[1] / 2;
    const int G = out_size / (2 * D + 1);
    const int* src = ei;
    const int* dst = ei + E;
    float* hidden = out + G;

    // workspace layout (~31 MB, all fully written before read)
    char* ws = (char*)d_ws;
    size_t off = 0;
    auto alloc = [&](size_t bytes) { void* p = ws + off; off += (bytes + 255) & ~(size_t)255; return p; };
    int*   counts = (int*)alloc((size_t)N * sizeof(int));          // histogram -> scatter cursor
    int*   rowptr = (int*)alloc((size_t)(N + 1) * sizeof(int));
    float* dinv   = (float*)alloc((size_t)N * sizeof(float));
    int*   ssrc   = (int*)alloc((size_t)E * sizeof(int));          // src ids sorted by dst
    float* buf0   = (float*)alloc((size_t)N * D * sizeof(float));  // activations h
    float* buf1   = (float*)alloc((size_t)N * D * sizeof(float));  // hws

    const int T = 256;

    // CSR build + dinv
    k_zero<<<(N + T - 1) / T, T, 0, stream>>>(counts, N);
    k_hist<<<(E + T - 1) / T, T, 0, stream>>>(dst, counts, E);
    k_dinv<<<(N + T - 1) / T, T, 0, stream>>>(counts, dinv, N);
    k_scan<<<1, 1024, 0, stream>>>(counts, rowptr, N);
    k_scatter<<<(E + T - 1) / T, T, 0, stream>>>(src, dst, counts, ssrc, E);

    auto layer = [&](const float* hin, int K, const float* W, const float* b) {
        if (K == 9)
            k_matmul<9><<<(N + 3) / 4, T, 0, stream>>>(hin, W, dinv, buf1, N);
        else
            k_matmul<64><<<(N + 3) / 4, T, 0, stream>>>(hin, W, dinv, buf1, N);
        k_aggregate<<<(N + 3) / 4, T, 0, stream>>>(rowptr, ssrc, dinv, buf1, b, buf0, N);
    };

    layer(x,    9,  W0, b0);
    layer(buf0, 64, W1, b1);
    layer(buf0, 64, W2, b2);
    layer(buf0, 64, W3, b3);

    k_pool<<<G, 64, 0, stream>>>(buf0, batch, Wout, bout, out, hidden, N);
}

// Round 12
// 601.290 us; speedup vs baseline: 2.3211x; 1.1461x over previous
//
#include <hip/hip_runtime.h>
#include <math.h>

#define D 64

// ---------------- CSR build ----------------
__global__ void k_zero(int* p, int n) {
    int i = blockIdx.x * blockDim.x + threadIdx.x;
    if (i < n) p[i] = 0;
}

__global__ void k_hist(const int* __restrict__ dst, int* __restrict__ counts, int e) {
    int i = blockIdx.x * blockDim.x + threadIdx.x;
    if (i < e) atomicAdd(&counts[dst[i]], 1);
}

// dinv = rsqrt(deg+1)  (self-loop included in degree)
__global__ void k_dinv(const int* __restrict__ counts, float* __restrict__ dinv, int n) {
    int i = blockIdx.x * blockDim.x + threadIdx.x;
    if (i < n) dinv[i] = rsqrtf((float)counts[i] + 1.0f);
}

// ---- 3-pass scan: block sums -> scan sums -> block exclusive scan + offset ----
__global__ void k_scan1(const int* __restrict__ counts, int* __restrict__ bsums, int n) {
    __shared__ int red[256];
    int i = blockIdx.x * 256 + threadIdx.x;
    red[threadIdx.x] = (i < n) ? counts[i] : 0;
    __syncthreads();
    for (int off = 128; off > 0; off >>= 1) {
        if (threadIdx.x < off) red[threadIdx.x] += red[threadIdx.x + off];
        __syncthreads();
    }
    if (threadIdx.x == 0) bsums[blockIdx.x] = red[0];
}

// single block; nb <= 1024. bsums -> exclusive prefix (in place). rowptr[n] = total.
__global__ void k_scan2(int* __restrict__ bsums, int* __restrict__ rowptr, int nb, int n) {
    __shared__ int part[1024];
    int t = threadIdx.x;
    part[t] = (t < nb) ? bsums[t] : 0;
    __syncthreads();
    for (int off = 1; off < 1024; off <<= 1) {
        int v = (t >= off) ? part[t - off] : 0;
        __syncthreads();
        part[t] += v;
        __syncthreads();
    }
    if (t < nb) bsums[t] = (t == 0) ? 0 : part[t - 1];
    if (t == 1023) rowptr[n] = part[1023];
}

// block-wide exclusive scan of counts + block offset -> rowptr; counts becomes scatter cursor
__global__ void k_scan3(int* __restrict__ counts, const int* __restrict__ bsums,
                        int* __restrict__ rowptr, int n) {
    __shared__ int part[256];
    int i = blockIdx.x * 256 + threadIdx.x;
    int t = threadIdx.x;
    int v = (i < n) ? counts[i] : 0;
    part[t] = v;
    __syncthreads();
    for (int off = 1; off < 256; off <<= 1) {
        int u = (t >= off) ? part[t - off] : 0;
        __syncthreads();
        part[t] += u;
        __syncthreads();
    }
    if (i < n) {
        int excl = bsums[blockIdx.x] + part[t] - v;   // inclusive - self = exclusive
        rowptr[i] = excl;
        counts[i] = excl;
    }
}

__global__ void k_scatter(const int* __restrict__ src, const int* __restrict__ dst,
                          int* __restrict__ cur, int* __restrict__ ssrc, int e) {
    int i = blockIdx.x * blockDim.x + threadIdx.x;
    if (i < e) { int p = atomicAdd(&cur[dst[i]], 1); ssrc[p] = src[i]; }
}

// ---------------- hws = (h @ W) * dinv[row] ----------------
template <int K>
__global__ void k_matmul(const float* __restrict__ h, const float* __restrict__ W,
                         const float* __restrict__ dinv, float* __restrict__ hws, int n) {
    __shared__ float sW[K * D];
    for (int i = threadIdx.x; i < K * D; i += blockDim.x) sW[i] = W[i];
    __syncthreads();
    int col = threadIdx.x & 63;
    int row = blockIdx.x * (blockDim.x >> 6) + (threadIdx.x >> 6);
    if (row >= n) return;
    const float* hr = h + (long)row * K;
    float acc = 0.0f;
#pragma unroll
    for (int k = 0; k < K; ++k) acc = fmaf(hr[k], sW[k * D + col], acc);
    hws[row * D + col] = acc * dinv[row];
}

// ---------------- pull-aggregate + bias + tanh (fused) ----------------
// agg[d] = dinv[d] * (sum_{s in N(d)} hws[s] + hws[d]);  h = tanh(agg + b)
__global__ void k_aggregate(const int* __restrict__ rowptr, const int* __restrict__ ssrc,
                            const float* __restrict__ dinv, const float* __restrict__ hws,
                            const float* __restrict__ b, float* __restrict__ hout, int n) {
    int node = blockIdx.x * (blockDim.x >> 6) + (threadIdx.x >> 6);
    int lane = threadIdx.x & 63;
    if (node >= n) return;
    int beg = rowptr[node], end = rowptr[node + 1];
    float acc = hws[node * D + lane];            // self-loop
    int e = beg;
    for (; e + 4 <= end; e += 4) {               // unroll-4 for load ILP
        int s0 = ssrc[e], s1 = ssrc[e + 1], s2 = ssrc[e + 2], s3 = ssrc[e + 3];
        float a0 = hws[s0 * D + lane], a1 = hws[s1 * D + lane];
        float a2 = hws[s2 * D + lane], a3 = hws[s3 * D + lane];
        acc += a0; acc += a1; acc += a2; acc += a3;
    }
    for (; e < end; ++e) acc += hws[ssrc[e] * D + lane];
    hout[node * D + lane] = tanhf(acc * dinv[node] + b[lane]);
}

// ---------------- per-graph pool + output head ----------------
__global__ void k_pool(const float* __restrict__ h, const int* __restrict__ batch,
                       const float* __restrict__ Wout, const float* __restrict__ bout,
                       float* __restrict__ out, float* __restrict__ hidden, int n) {
    int g = blockIdx.x;
    int lo = 0, hi = n;
    while (lo < hi) { int mid = (lo + hi) >> 1; if (batch[mid] < g) lo = mid + 1; else hi = mid; }
    int start = lo;
    hi = n;
    while (lo < hi) { int mid = (lo + hi) >> 1; if (batch[mid] < g + 1) lo = mid + 1; else hi = mid; }
    int end = lo;

    int j = threadIdx.x;
    float mx = -INFINITY, sm = 0.0f;
    for (int nd = start; nd < end; ++nd) {
        float v = h[nd * D + j];
        mx = fmaxf(mx, v);
        sm += v;
    }
    float gmax  = (end > start) ? mx : 0.0f;
    float gmean = sm / fmaxf((float)(end - start), 1.0f);

    hidden[g * 2 * D + j]     = gmax;
    hidden[g * 2 * D + D + j] = gmean;

    float p = gmax * Wout[j] + gmean * Wout[D + j];
#pragma unroll
    for (int off = 32; off > 0; off >>= 1) p += __shfl_down(p, off, 64);
    if (j == 0) out[g] = p + bout[0];
}

extern "C" void kernel_launch(void* const* d_in, const int* in_sizes, int n_in,
                              void* d_out, int out_size, void* d_ws, size_t ws_size,
                              hipStream_t stream) {
    const float* x     = (const float*)d_in[0];
    const int*   ei    = (const int*)d_in[1];
    const int*   batch = (const int*)d_in[2];
    const float* W0 = (const float*)d_in[3];  const float* b0 = (const float*)d_in[4];
    const float* W1 = (const float*)d_in[5];  const float* b1 = (const float*)d_in[6];
    const float* W2 = (const float*)d_in[7];  const float* b2 = (const float*)d_in[8];
    const float* W3 = (const float*)d_in[9];  const float* b3 = (const float*)d_in[10];
    const float* Wout = (const float*)d_in[11];
    const float* bout = (const float*)d_in[12];
    float* out = (float*)d_out;

    const int N = in_sizes[0] / 9;
    const int E = in_sizes[1] / 2;
    const int G = out_size / (2 * D + 1);
    const int* src = ei;
    const int* dst = ei + E;
    float* hidden = out + G;

    // workspace layout (~31 MB, all fully written before read)
    char* ws = (char*)d_ws;
    size_t off = 0;
    auto alloc = [&](size_t bytes) { void* p = ws + off; off += (bytes + 255) & ~(size_t)255; return p; };
    int*   counts = (int*)alloc((size_t)N * sizeof(int));          // histogram -> scatter cursor
    int*   rowptr = (int*)alloc((size_t)(N + 1) * sizeof(int));
    float* dinv   = (float*)alloc((size_t)N * sizeof(float));
    int*   ssrc   = (int*)alloc((size_t)E * sizeof(int));          // src ids sorted by dst
    int*   bsums  = (int*)alloc(1024 * sizeof(int));               // per-block sums for scan
    float* buf0   = (float*)alloc((size_t)N * D * sizeof(float));  // activations h
    float* buf1   = (float*)alloc((size_t)N * D * sizeof(float));  // hws

    const int T = 256;
    const int nb = (N + 255) / 256;   // scan blocks (<= 1024)

    // CSR build + dinv
    k_zero<<<(N + T - 1) / T, T, 0, stream>>>(counts, N);
    k_hist<<<(E + T - 1) / T, T, 0, stream>>>(dst, counts, E);
    k_dinv<<<(N + T - 1) / T, T, 0, stream>>>(counts, dinv, N);
    k_scan1<<<nb, 256, 0, stream>>>(counts, bsums, N);
    k_scan2<<<1, 1024, 0, stream>>>(bsums, rowptr, nb, N);
    k_scan3<<<nb, 256, 0, stream>>>(counts, bsums, rowptr, N);
    k_scatter<<<(E + T - 1) / T, T, 0, stream>>>(src, dst, counts, ssrc, E);

    auto layer = [&](const float* hin, int K, const float* W, const float* b) {
        if (K == 9)
            k_matmul<9><<<(N + 3) / 4, T, 0, stream>>>(hin, W, dinv, buf1, N);
        else
            k_matmul<64><<<(N + 3) / 4, T, 0, stream>>>(hin, W, dinv, buf1, N);
        k_aggregate<<<(N + 3) / 4, T, 0, stream>>>(rowptr, ssrc, dinv, buf1, b, buf0, N);
    };

    layer(x,    9,  W0, b0);
    layer(buf0, 64, W1, b1);
    layer(buf0, 64, W2, b2);
    layer(buf0, 64, W3, b3);

    k_pool<<<G, 64, 0, stream>>>(buf0, batch, Wout, bout, out, hidden, N);
}

// Round 19
// 542.102 us; speedup vs baseline: 2.5745x; 1.1092x over previous
//
#include <hip/hip_runtime.h>
#include <math.h>

#define D 64
#define CHUNK 8192      // edges per workgroup (4 waves x 2048)
#define WAVE_E 2048
#define ITER 32         // WAVE_E / 64

// Edge word packing: w = (dst<<16) | src. Requires N <= 65536 (problem: N=50000).

// ---------------- radix histogram (256 bins of key byte) ----------------
template <int SHIFT, bool PACKED>
__global__ void k_rhist(const void* __restrict__ keysrc, int* __restrict__ gmat,
                        int e, int nwg) {
    __shared__ int hist[256];
    int t = threadIdx.x, wg = blockIdx.x;
    hist[t] = 0;
    __syncthreads();
    int base = wg * CHUNK;
    int lim = min(CHUNK, e - base);
    for (int i = t; i < lim; i += 256) {
        unsigned int key;
        if (PACKED) key = ((const unsigned int*)keysrc)[base + i] >> 16;
        else        key = (unsigned int)((const int*)keysrc)[base + i];
        atomicAdd(&hist[(key >> SHIFT) & 255], 1);
    }
    __syncthreads();
    gmat[t * nwg + wg] = hist[t];   // bin-major matrix for the scan
}

// ---------------- generic 3-pass exclusive scan (in place) ----------------
__global__ void k_scanA(const int* __restrict__ a, int* __restrict__ bsums, int n) {
    __shared__ int red[256];
    int i = blockIdx.x * 256 + threadIdx.x;
    red[threadIdx.x] = (i < n) ? a[i] : 0;
    __syncthreads();
    for (int off = 128; off > 0; off >>= 1) {
        if (threadIdx.x < off) red[threadIdx.x] += red[threadIdx.x + off];
        __syncthreads();
    }
    if (threadIdx.x == 0) bsums[blockIdx.x] = red[0];
}
__global__ void k_scanB(int* __restrict__ bsums, int nb) {
    __shared__ int part[1024];
    int t = threadIdx.x;
    part[t] = (t < nb) ? bsums[t] : 0;
    __syncthreads();
    for (int off = 1; off < 1024; off <<= 1) {
        int v = (t >= off) ? part[t - off] : 0;
        __syncthreads();
        part[t] += v;
        __syncthreads();
    }
    if (t < nb) bsums[t] = (t == 0) ? 0 : part[t - 1];
}
__global__ void k_scanC(int* __restrict__ a, const int* __restrict__ bsums, int n) {
    __shared__ int part[256];
    int i = blockIdx.x * 256 + threadIdx.x;
    int t = threadIdx.x;
    int v = (i < n) ? a[i] : 0;
    part[t] = v;
    __syncthreads();
    for (int off = 1; off < 256; off <<= 1) {
        int u = (t >= off) ? part[t - off] : 0;
        __syncthreads();
        part[t] += u;
        __syncthreads();
    }
    if (i < n) a[i] = bsums[blockIdx.x] + part[t] - v;   // exclusive + block offset
}

// ---------------- stable radix scatter (atomic-free at global scope) ----------------
template <int SHIFT>
__global__ void k_rscat(const int* __restrict__ src, const int* __restrict__ dst,
                        const unsigned int* __restrict__ inp, const int* __restrict__ gmat,
                        unsigned int* __restrict__ outp, int e, int nwg) {
    __shared__ int whist[4][256];
    __shared__ int cnt[4][256];
    int t = threadIdx.x, wg = blockIdx.x;
    int wave = t >> 6, lane = t & 63;
    for (int w = 0; w < 4; ++w) whist[w][t] = 0;
    __syncthreads();
    int qbase = wg * CHUNK + wave * WAVE_E;
    // wave-private histogram (order-free)
    for (int it = 0; it < ITER; ++it) {
        int idx = qbase + it * 64 + lane;
        if (idx < e) {
            unsigned int w32 = (SHIFT == 0)
                ? (((unsigned int)dst[idx] << 16) | (unsigned int)src[idx])
                : inp[idx];
            atomicAdd(&whist[wave][(w32 >> (16 + SHIFT)) & 255], 1);
        }
    }
    __syncthreads();
    // per-wave base cursors: global base + earlier waves in this chunk
    {
        int g = gmat[t * nwg + wg];          // t = bin
        cnt[0][t] = g;
        g += whist[0][t]; cnt[1][t] = g;
        g += whist[1][t]; cnt[2][t] = g;
        g += whist[2][t]; cnt[3][t] = g;
    }
    __syncthreads();
    // stable scatter: rank = iteration-order LDS cursor + in-wave ballot rank
    for (int it = 0; it < ITER; ++it) {
        int idx = qbase + it * 64 + lane;
        bool valid = idx < e;
        unsigned int w32 = 0; int bin = 0;
        if (valid) {
            w32 = (SHIFT == 0)
                ? (((unsigned int)dst[idx] << 16) | (unsigned int)src[idx])
                : inp[idx];
            bin = (w32 >> (16 + SHIFT)) & 255;
        }
        unsigned long long same = ~0ULL;
        for (int b = 0; b < 8; ++b) {
            unsigned long long vote = __ballot((bin >> b) & 1);
            same &= ((bin >> b) & 1) ? vote : ~vote;
        }
        same &= __ballot(valid);
        if (valid) {
            int leader = __ffsll(same) - 1;
            int rank = __popcll(same & ((1ULL << lane) - 1));
            int old = 0;
            if (lane == leader) old = atomicAdd(&cnt[wave][bin], (int)__popcll(same));
            old = __shfl(old, leader, 64);
            outp[old + rank] = w32;
        }
    }
}

// ---------------- rowptr via binary search over sorted keys ----------------
__global__ void k_rowptr(const unsigned int* __restrict__ sp, int* __restrict__ rowptr,
                         int n, int e) {
    int d = blockIdx.x * blockDim.x + threadIdx.x;
    if (d > n) return;
    if (d == n) { rowptr[n] = e; return; }
    unsigned int ud = (unsigned int)d;
    int lo = 0, hi = e;
    while (lo < hi) { int m = (lo + hi) >> 1; if ((sp[m] >> 16) < ud) lo = m + 1; else hi = m; }
    rowptr[d] = lo;
}

__global__ void k_dinv2(const int* __restrict__ rowptr, float* __restrict__ dinv, int n) {
    int i = blockIdx.x * blockDim.x + threadIdx.x;
    if (i < n) dinv[i] = rsqrtf((float)(rowptr[i + 1] - rowptr[i]) + 1.0f);
}

// ---------------- hws = (h @ W) * dinv[row] ----------------
template <int K>
__global__ void k_matmul(const float* __restrict__ h, const float* __restrict__ W,
                         const float* __restrict__ dinv, float* __restrict__ hws, int n) {
    __shared__ float sW[K * D];
    for (int i = threadIdx.x; i < K * D; i += blockDim.x) sW[i] = W[i];
    __syncthreads();
    int col = threadIdx.x & 63;
    int row = blockIdx.x * (blockDim.x >> 6) + (threadIdx.x >> 6);
    if (row >= n) return;
    const float* hr = h + (long)row * K;
    float acc = 0.0f;
#pragma unroll
    for (int k = 0; k < K; ++k) acc = fmaf(hr[k], sW[k * D + col], acc);
    hws[row * D + col] = acc * dinv[row];
}

// ---------------- pull-aggregate + bias + tanh (fused) ----------------
__global__ void k_aggregate(const int* __restrict__ rowptr, const unsigned int* __restrict__ sp,
                            const float* __restrict__ dinv, const float* __restrict__ hws,
                            const float* __restrict__ b, float* __restrict__ hout, int n) {
    int node = blockIdx.x * (blockDim.x >> 6) + (threadIdx.x >> 6);
    int lane = threadIdx.x & 63;
    if (node >= n) return;
    int beg = rowptr[node], end = rowptr[node + 1];
    float acc = hws[node * D + lane];            // self-loop
    int e = beg;
    for (; e + 4 <= end; e += 4) {
        int s0 = sp[e] & 0xFFFF, s1 = sp[e + 1] & 0xFFFF;
        int s2 = sp[e + 2] & 0xFFFF, s3 = sp[e + 3] & 0xFFFF;
        float a0 = hws[s0 * D + lane], a1 = hws[s1 * D + lane];
        float a2 = hws[s2 * D + lane], a3 = hws[s3 * D + lane];
        acc += a0; acc += a1; acc += a2; acc += a3;
    }
    for (; e < end; ++e) acc += hws[(sp[e] & 0xFFFF) * D + lane];
    hout[node * D + lane] = tanhf(acc * dinv[node] + b[lane]);
}

// ---------------- per-graph pool + output head ----------------
__global__ void k_pool(const float* __restrict__ h, const int* __restrict__ batch,
                       const float* __restrict__ Wout, const float* __restrict__ bout,
                       float* __restrict__ out, float* __restrict__ hidden, int n) {
    int g = blockIdx.x;
    int lo = 0, hi = n;
    while (lo < hi) { int mid = (lo + hi) >> 1; if (batch[mid] < g) lo = mid + 1; else hi = mid; }
    int start = lo;
    hi = n;
    while (lo < hi) { int mid = (lo + hi) >> 1; if (batch[mid] < g + 1) lo = mid + 1; else hi = mid; }
    int end = lo;

    int j = threadIdx.x;
    float mx = -INFINITY, sm = 0.0f;
    for (int nd = start; nd < end; ++nd) {
        float v = h[nd * D + j];
        mx = fmaxf(mx, v);
        sm += v;
    }
    float gmax  = (end > start) ? mx : 0.0f;
    float gmean = sm / fmaxf((float)(end - start), 1.0f);

    hidden[g * 2 * D + j]     = gmax;
    hidden[g * 2 * D + D + j] = gmean;

    float p = gmax * Wout[j] + gmean * Wout[D + j];
#pragma unroll
    for (int off = 32; off > 0; off >>= 1) p += __shfl_down(p, off, 64);
    if (j == 0) out[g] = p + bout[0];
}

extern "C" void kernel_launch(void* const* d_in, const int* in_sizes, int n_in,
                              void* d_out, int out_size, void* d_ws, size_t ws_size,
                              hipStream_t stream) {
    const float* x     = (const float*)d_in[0];
    const int*   ei    = (const int*)d_in[1];
    const int*   batch = (const int*)d_in[2];
    const float* W0 = (const float*)d_in[3];  const float* b0 = (const float*)d_in[4];
    const float* W1 = (const float*)d_in[5];  const float* b1 = (const float*)d_in[6];
    const float* W2 = (const float*)d_in[7];  const float* b2 = (const float*)d_in[8];
    const float* W3 = (const float*)d_in[9];  const float* b3 = (const float*)d_in[10];
    const float* Wout = (const float*)d_in[11];
    const float* bout = (const float*)d_in[12];
    float* out = (float*)d_out;

    const int N = in_sizes[0] / 9;
    const int E = in_sizes[1] / 2;
    const int G = out_size / (2 * D + 1);
    const int* src = ei;
    const int* dst = ei + E;
    float* hidden = out + G;

    const int nwg  = (E + CHUNK - 1) / CHUNK;     // radix workgroups (147)
    const int glen = 256 * nwg;
    const int nbg  = (glen + 255) / 256;          // = nwg <= 1024

    // workspace (~31 MB): bufA aliased under buf0 (dead before first aggregate)
    char* ws = (char*)d_ws;
    size_t off = 0;
    auto alloc = [&](size_t bytes) { void* p = ws + off; off += (bytes + 255) & ~(size_t)255; return p; };
    unsigned int* bufB  = (unsigned int*)alloc((size_t)E * 4);        // sorted edge words
    int*   gmat   = (int*)alloc((size_t)glen * 4);
    int*   bsums  = (int*)alloc(1024 * 4);
    int*   rowptr = (int*)alloc((size_t)(N + 1) * 4);
    float* dinv   = (float*)alloc((size_t)N * 4);
    float* buf1   = (float*)alloc((size_t)N * D * 4);                 // hws
    float* buf0   = (float*)alloc((size_t)N * D * 4);                 // activations
    unsigned int* bufA = (unsigned int*)buf0;                         // pass-1 output (alias)

    const int T = 256;

    // ---- atomic-free CSR build: 2-pass LSD radix sort by dst ----
    k_rhist<0, false><<<nwg, 256, 0, stream>>>(dst, gmat, E, nwg);
    k_scanA<<<nbg, 256, 0, stream>>>(gmat, bsums, glen);
    k_scanB<<<1, 1024, 0, stream>>>(bsums, nbg);
    k_scanC<<<nbg, 256, 0, stream>>>(gmat, bsums, glen);
    k_rscat<0><<<nwg, 256, 0, stream>>>(src, dst, nullptr, gmat, bufA, E, nwg);

    k_rhist<8, true><<<nwg, 256, 0, stream>>>(bufA, gmat, E, nwg);
    k_scanA<<<nbg, 256, 0, stream>>>(gmat, bsums, glen);
    k_scanB<<<1, 1024, 0, stream>>>(bsums, nbg);
    k_scanC<<<nbg, 256, 0, stream>>>(gmat, bsums, glen);
    k_rscat<8><<<nwg, 256, 0, stream>>>(nullptr, nullptr, bufA, gmat, bufB, E, nwg);

    k_rowptr<<<(N + 1 + T - 1) / T, T, 0, stream>>>(bufB, rowptr, N, E);
    k_dinv2<<<(N + T - 1) / T, T, 0, stream>>>(rowptr, dinv, N);

    // ---- 4 GCN layers ----
    auto layer = [&](const float* hin, int K, const float* W, const float* b) {
        if (K == 9)
            k_matmul<9><<<(N + 3) / 4, T, 0, stream>>>(hin, W, dinv, buf1, N);
        else
            k_matmul<64><<<(N + 3) / 4, T, 0, stream>>>(hin, W, dinv, buf1, N);
        k_aggregate<<<(N + 3) / 4, T, 0, stream>>>(rowptr, bufB, dinv, buf1, b, buf0, N);
    };

    layer(x,    9,  W0, b0);
    layer(buf0, 64, W1, b1);
    layer(buf0, 64, W2, b2);
    layer(buf0, 64, W3, b3);

    k_pool<<<G, 64, 0, stream>>>(buf0, batch, Wout, bout, out, hidden, N);
}